// Round 4
// baseline (71.149 us; speedup 1.0000x reference)
//
#include <hip/hip_runtime.h>
#include <math.h>

#define HH 512
#define WW 512
#define M 2048          // 64 segs * 32 samples = path points / edges
#define TPB 256
#define HALF 256        // pixels owned by one block
#define TWIN 18         // sigmoid truncation half-width (err <= e^-18 per edge)
#define WPIX 37         // 2*TWIN+1 window pixels
#define EPB 6           // edges per dense pass (6*37 = 222 lanes)
#define MAXACT 2048

// fast sigmoid: v_exp + v_rcp (1-ulp; error budget has ~5x margin)
__device__ __forceinline__ float sigmoidf(float z) {
    return __builtin_amdgcn_rcpf(1.0f + __expf(-z));
}

__global__ __launch_bounds__(TPB) void bezier_render_kernel(
    const float* __restrict__ cp,     // 193*2 floats
    const float* __restrict__ color,  // 3 floats
    float* __restrict__ out)          // H*W*4 floats
{
    __shared__ float2 cps2[194];       // control points
    __shared__ float  smoothv[HALF];   // windowed exact part (local x)
    __shared__ float  cbin[HALF + 1];  // step-part bins (local x)
    __shared__ float  wtot[4];         // per-wave scan totals
    __shared__ float2 act[MAXACT];     // compacted (x_cross, w)
    __shared__ int    nact;

    const int t    = threadIdx.x;
    const int lane = t & 63;
    const int wv   = t >> 6;
    const int y    = blockIdx.x >> 1;           // row
    const int xlo  = (blockIdx.x & 1) * HALF;   // this block's pixel range start
    const float gy = (float)y;

    // hoist tiny global loads; latency hidden behind phases 0-1
    float rC = color[0], gC = color[1], bC = color[2];

    // ---- 0) stage control points; zero accumulators ----
    if (t < 193) cps2[t] = ((const float2*)cp)[t];
    if (t == 0) { nact = 0; cbin[HALF] = 0.0f; }
    smoothv[t] = 0.0f;
    cbin[t]    = 0.0f;
    __syncthreads();

    // ---- 1) edge scan: endpoints recomputed from control points (no pts LDS) ----
    // point(m): s=m>>5, i=m&31, t=i/31 cubic bezier eval. i==31 of seg s equals
    // i==0 of seg s+1 exactly (t=0 -> w0=1), so generic eval handles the wrap.
    for (int e = t; e < M; e += TPB) {
        int m2 = (e + 1) & (M - 1);
        int s1 = e >> 5,  i1 = e & 31;
        int s2 = m2 >> 5, i2 = m2 & 31;
        float ta = (float)i1 * (1.0f / 31.0f);
        float tb = (float)i2 * (1.0f / 31.0f);
        float2 A0 = cps2[3*s1], A1 = cps2[3*s1+1], A2 = cps2[3*s1+2], A3 = cps2[3*s1+3];
        float mta = 1.0f - ta;
        float wa0 = mta*mta*mta, wa1 = 3.0f*mta*mta*ta, wa2 = 3.0f*mta*ta*ta, wa3 = ta*ta*ta;
        float axp = wa0*A0.x + wa1*A1.x + wa2*A2.x + wa3*A3.x;
        float ayp = wa0*A0.y + wa1*A1.y + wa2*A2.y + wa3*A3.y;
        float2 B0 = cps2[3*s2], B1 = cps2[3*s2+1], B2 = cps2[3*s2+2], B3 = cps2[3*s2+3];
        float mtb = 1.0f - tb;
        float wb0 = mtb*mtb*mtb, wb1 = 3.0f*mtb*mtb*tb, wb2 = 3.0f*mtb*tb*tb, wb3 = tb*tb*tb;
        float bxp = wb0*B0.x + wb1*B1.x + wb2*B2.x + wb3*B3.x;
        float byp = wb0*B0.y + wb1*B1.y + wb2*B2.y + wb3*B3.y;

        float dy = byp - ayp;
        float tc = (gy - ayp) * __builtin_amdgcn_rcpf(dy + 1e-8f);
        // valid_t < 1e-7 outside (-0.8059, 1.8059); NaN tc fails compares.
        if (!(fabsf(dy) >= 1e-6f) || !(tc > -0.8059f) || !(tc < 1.8059f)) continue;
        float ea = __expf(-20.0f * tc);
        float eb = __expf(-20.0f * (1.0f - tc));
        float v = __builtin_amdgcn_rcpf((1.0f + ea) * (1.0f + eb));
        float w = (dy > 0.0f) ? v : -v;                 // valid_t * sign(dy)
        float xc = fmaf(tc, bxp - axp, axp);
        int A = (int)floorf(xc) - TWIN;                 // first windowed pixel (global)
        int binL = A - xlo;                             // local pixels x<binL get full w
        if (binL > HALF) binL = HALF;
        if (binL > 0) atomicAdd(&cbin[binL], w);
        int rel = A - xlo;                              // window = [rel, rel+36] local
        if (rel < HALF && rel > -WPIX) {
            int idx = atomicAdd(&nact, 1);
            act[idx] = make_float2(xc, w);
        }
    }
    __syncthreads();

    // ---- 2) dense windowed pass: 37 lanes/edge, 6 edges/pass ----
    {
        int na = nact;
        int el = t / WPIX;               // 0..6 (lanes 222..255 idle)
        int k  = t - el * WPIX;          // 0..36
        if (el < EPB) {
            for (int e = el; e < na; e += EPB) {
                float2 xw = act[e];
                int x = (int)floorf(xw.x) - TWIN + k - xlo;   // local coord
                if ((unsigned)x < (unsigned)HALF) {
                    atomicAdd(&smoothv[x], xw.y * sigmoidf(xw.x - (float)(x + xlo)));
                }
            }
        }
    }
    __syncthreads();

    // ---- 3) suffix scan: wind_const[t] = sum_{j>t} cbin[j] (incl. cbin[256]) ----
    float p = cbin[t];
    float v = p;
#pragma unroll
    for (int off = 1; off < 64; off <<= 1) {
        float o = __shfl_down(v, off, 64);
        if (lane + off < 64) v += o;
    }
    if (lane == 0) wtot[wv] = v;
    __syncthreads();
    float hsum = cbin[HALF];
    if (wv < 1) hsum += wtot[1];
    if (wv < 2) hsum += wtot[2];
    if (wv < 3) hsum += wtot[3];

    // ---- 4) alpha + one coalesced float4 per thread ----
    float wind = (v - p) + hsum + smoothv[t];
    float a = sigmoidf(4.0f * wind);
    ((float4*)out)[y * WW + xlo + t] = make_float4(rC, gC, bC, a);
}

extern "C" void kernel_launch(void* const* d_in, const int* in_sizes, int n_in,
                              void* d_out, int out_size, void* d_ws, size_t ws_size,
                              hipStream_t stream) {
    const float* cp    = (const float*)d_in[0];  // (193,2) float32
    const float* color = (const float*)d_in[1];  // (3,) float32
    float* out = (float*)d_out;                  // (512,512,4) float32
    bezier_render_kernel<<<dim3(HH * 2), dim3(TPB), 0, stream>>>(cp, color, out);
}